// Round 4
// baseline (1505.134 us; speedup 1.0000x reference)
//
#include <hip/hip_runtime.h>
#include <hip/hip_bf16.h>

#define DEVI __device__ __forceinline__

constexpr int T_ = 64;   // window
constexpr int F_ = 16;   // features
constexpr int H_ = 128;  // hidden
constexpr int G_ = 512;  // 4*H gates
constexpr int NSEQ_ = 1024;  // B*M

DEVI float sigmoidf_(float x) { return 1.0f / (1.0f + __expf(-x)); }
DEVI float tanhf_(float x) {
    float a = fabsf(x);
    float e = __expf(-2.0f * a);
    float r = (1.0f - e) / (1.0f + e);
    return copysignf(r, x);
}

// One block per sequence n (0..1023), 512 threads.
// Thread tid owns gate row tid of W_hh (128 floats in VGPRs).
// LDS ~46.8 KB.
__global__
void lstm_ha_qkv(const float* __restrict__ x,
                 const float* __restrict__ W_ih, const float* __restrict__ W_hh,
                 const float* __restrict__ b_ih, const float* __restrict__ b_hh,
                 const float* __restrict__ w1, const float* __restrict__ b1,
                 const float* __restrict__ w2, const float* __restrict__ b2,
                 const float* __restrict__ wa, const float* __restrict__ ba,
                 const float* __restrict__ wq, const float* __restrict__ bq,
                 const float* __restrict__ wk, const float* __restrict__ bk,
                 const float* __restrict__ wv, const float* __restrict__ bv,
                 float* __restrict__ qout, float* __restrict__ kout,
                 float* __restrict__ vout)
{
    __shared__ alignas(16) float xs[T_ * F_];      // 4 KB
    __shared__ alignas(16) float hbuf[H_];
    __shared__ alignas(16) float cbuf[H_];
    __shared__ alignas(16) float gbuf[G_];         // 2 KB
    __shared__ alignas(16) float rep[T_][H_];      // 32 KB
    __shared__ alignas(16) float pA[4][H_], pB[4][H_], pC[4][H_];  // 6 KB
    __shared__ alignas(16) float a2s[H_];
    __shared__ alignas(16) float alphas[T_];
    __shared__ alignas(16) float srbuf[H_];
    __shared__ alignas(16) float red2[4][16][2];

    const int n   = blockIdx.x;
    const int tid = threadIdx.x;
    const int o   = tid & (H_ - 1);
    const int jc  = tid >> 7;              // 0..3 (uniform per wave)

    for (int i = tid; i < T_ * F_; i += 512) xs[i] = x[n * (T_ * F_) + i];
    if (tid < H_) { hbuf[tid] = 0.0f; cbuf[tid] = 0.0f; }

    // ---- preload weights into registers ----
    float wih[F_];
    {
        const float4* p = (const float4*)(W_ih + tid * F_);
        #pragma unroll
        for (int i = 0; i < 4; ++i) {
            float4 v4 = p[i];
            wih[4*i+0] = v4.x; wih[4*i+1] = v4.y; wih[4*i+2] = v4.z; wih[4*i+3] = v4.w;
        }
    }
    float whh[H_];
    {
        const float4* p = (const float4*)(W_hh + tid * H_);
        #pragma unroll
        for (int i = 0; i < 32; ++i) {
            float4 v4 = p[i];
            whh[4*i+0] = v4.x; whh[4*i+1] = v4.y; whh[4*i+2] = v4.z; whh[4*i+3] = v4.w;
        }
    }
    const float bias = b_ih[tid] + b_hh[tid];
    __syncthreads();

    // ---- recurrent loop ----
    #pragma unroll 1
    for (int t = 0; t < T_; ++t) {
        float a0 = bias, a1v = 0.f, a2v = 0.f, a3v = 0.f;
        {
            const float4* xp = (const float4*)(xs + t * F_);
            #pragma unroll
            for (int i = 0; i < 4; ++i) {
                float4 xv = xp[i];
                a0  += wih[4*i+0] * xv.x; a1v += wih[4*i+1] * xv.y;
                a2v += wih[4*i+2] * xv.z; a3v += wih[4*i+3] * xv.w;
            }
        }
        {
            const float4* hp = (const float4*)hbuf;
            #pragma unroll
            for (int i = 0; i < 32; ++i) {
                float4 hv = hp[i];
                a0  += whh[4*i+0] * hv.x; a1v += whh[4*i+1] * hv.y;
                a2v += whh[4*i+2] * hv.z; a3v += whh[4*i+3] * hv.w;
            }
        }
        gbuf[tid] = (a0 + a1v) + (a2v + a3v);
        __syncthreads();

        if (tid < H_) {
            float gi = sigmoidf_(gbuf[tid]);
            float gf = sigmoidf_(gbuf[H_ + tid]);
            float gg = tanhf_(gbuf[2 * H_ + tid]);
            float go = sigmoidf_(gbuf[3 * H_ + tid]);
            float c  = gf * cbuf[tid] + gi * gg;
            float h  = go * tanhf_(c);
            cbuf[tid] = c; hbuf[tid] = h; rep[t][tid] = h;
        }
        __syncthreads();
    }

    // ---- a2 = h[63] @ w2^T (+ b1 + b2 folded in) ----
    {
        float r0=0.f,r1=0.f,r2=0.f,r3=0.f;
        const float4* hq  = (const float4*)(hbuf + jc * 32);
        const float4* w2p = (const float4*)(w2 + o * H_ + jc * 32);
        #pragma unroll
        for (int i = 0; i < 8; ++i) {
            float4 hv = hq[i]; float4 wv2 = w2p[i];
            r0 += wv2.x * hv.x; r1 += wv2.y * hv.y;
            r2 += wv2.z * hv.z; r3 += wv2.w * hv.w;
        }
        pB[jc][o] = (r0 + r1) + (r2 + r3);
        __syncthreads();
        if (tid < H_)
            a2s[tid] = (pB[0][tid] + pB[1][tid]) + (pB[2][tid] + pB[3][tid])
                       + b1[tid] + b2[tid];
        __syncthreads();
    }

    // ---- alpha logits: logit[t] = sum_o wa[o]*tanh(w1[o].rep[t] + a2s[o]) ----
    // Thread (o, jc) holds the full w1 row o (whh regs dead now) and covers
    // t = jc*16 .. jc*16+15. rep[t] reads are wave-uniform -> LDS broadcast.
    {
        float w1row[H_];
        {
            const float4* p = (const float4*)(w1 + o * H_);
            #pragma unroll
            for (int i = 0; i < 32; ++i) {
                float4 v4 = p[i];
                w1row[4*i+0] = v4.x; w1row[4*i+1] = v4.y;
                w1row[4*i+2] = v4.z; w1row[4*i+3] = v4.w;
            }
        }
        const float wao = wa[o];
        const float a2o = a2s[o];
        for (int tt = 0; tt < 16; ++tt) {
            const int t = jc * 16 + tt;
            const float4* rp = (const float4*)(&rep[t][0]);
            float d0=0.f,d1=0.f,d2=0.f,d3=0.f;
            #pragma unroll
            for (int i = 0; i < 32; ++i) {
                float4 rv = rp[i];
                d0 += w1row[4*i+0] * rv.x; d1 += w1row[4*i+1] * rv.y;
                d2 += w1row[4*i+2] * rv.z; d3 += w1row[4*i+3] * rv.w;
            }
            float s = wao * tanhf_(((d0 + d1) + (d2 + d3)) + a2o);
            s += __shfl_xor(s, 1);  s += __shfl_xor(s, 2);  s += __shfl_xor(s, 4);
            s += __shfl_xor(s, 8);  s += __shfl_xor(s, 16); s += __shfl_xor(s, 32);
            if ((tid & 63) == 0) red2[jc][tt][(tid >> 6) & 1] = s;
        }
        __syncthreads();
    }

    // ---- softmax over the 64 logits (wave 0) ----
    if (tid < T_) {
        float vl = red2[tid >> 4][tid & 15][0] + red2[tid >> 4][tid & 15][1] + ba[0];
        float m = vl;
        #pragma unroll
        for (int off = 1; off < 64; off <<= 1) m = fmaxf(m, __shfl_xor(m, off));
        float e = __expf(vl - m);
        float ssum = e;
        #pragma unroll
        for (int off = 1; off < 64; off <<= 1) ssum += __shfl_xor(ssum, off);
        alphas[tid] = e / ssum;
    }
    __syncthreads();

    // ---- stock_rep = sum_t alpha[t] * rep[t] ----
    {
        float s = 0.f;
        #pragma unroll
        for (int i = 0; i < 16; ++i) {
            int t = jc * 16 + i;
            s += alphas[t] * rep[t][o];
        }
        pA[jc][o] = s;
        __syncthreads();
        if (tid < H_)
            srbuf[tid] = (pA[0][tid] + pA[1][tid]) + (pA[2][tid] + pA[3][tid]);
        __syncthreads();
    }

    // ---- q,k,v projections of stock_rep ----
    {
        float aq0=0.f,aq1=0.f, ak0=0.f,ak1=0.f, av0=0.f,av1=0.f;
        const float4* sp  = (const float4*)(srbuf + jc * 32);
        const float4* wqp = (const float4*)(wq + o * H_ + jc * 32);
        const float4* wkp = (const float4*)(wk + o * H_ + jc * 32);
        const float4* wvp = (const float4*)(wv + o * H_ + jc * 32);
        #pragma unroll
        for (int i = 0; i < 8; ++i) {
            float4 sv = sp[i];
            float4 q4 = wqp[i], k4 = wkp[i], v4 = wvp[i];
            aq0 += q4.x * sv.x + q4.z * sv.z; aq1 += q4.y * sv.y + q4.w * sv.w;
            ak0 += k4.x * sv.x + k4.z * sv.z; ak1 += k4.y * sv.y + k4.w * sv.w;
            av0 += v4.x * sv.x + v4.z * sv.z; av1 += v4.y * sv.y + v4.w * sv.w;
        }
        pA[jc][o] = aq0 + aq1; pB[jc][o] = ak0 + ak1; pC[jc][o] = av0 + av1;
        __syncthreads();
        if (tid < H_) {
            qout[n * H_ + tid] = (pA[0][tid]+pA[1][tid]) + (pA[2][tid]+pA[3][tid]) + bq[tid];
            kout[n * H_ + tid] = (pB[0][tid]+pB[1][tid]) + (pB[2][tid]+pB[3][tid]) + bk[tid];
            vout[n * H_ + tid] = (pC[0][tid]+pC[1][tid]) + (pC[2][tid]+pC[3][tid]) + bv[tid];
        }
    }
}

// Cross-asset attention: one block per (b, m) query row, 256 threads.
// Output is FLOAT32 (reference returns jnp.float32).
__global__
void caan(const float* __restrict__ qb, const float* __restrict__ kb,
          const float* __restrict__ vb, const float* __restrict__ ww,
          const float* __restrict__ bw, float* __restrict__ out)
{
    __shared__ alignas(16) float qs[H_];
    __shared__ alignas(16) float sc[512];
    __shared__ alignas(16) float red[8];
    __shared__ alignas(16) float pv[2][H_];

    const int n   = blockIdx.x;       // 0..1023
    const int b   = n >> 9;
    const int tid = threadIdx.x;

    if (tid < H_) qs[tid] = qb[n * H_ + tid];
    __syncthreads();

    const float scale = 0.08838834764831845f;  // 1/sqrt(128)
    float s0raw = 0.f, s1raw = 0.f;
    #pragma unroll
    for (int r = 0; r < 2; ++r) {
        const int j = tid + r * 256;
        const float4* kp = (const float4*)(kb + (size_t)(b * 512 + j) * H_);
        const float4* qp = (const float4*)qs;
        float c0=0.f,c1=0.f,c2=0.f,c3=0.f;
        #pragma unroll
        for (int i = 0; i < 32; ++i) {
            float4 kv = kp[i], qv = qp[i];
            c0 += kv.x * qv.x; c1 += kv.y * qv.y;
            c2 += kv.z * qv.z; c3 += kv.w * qv.w;
        }
        float sres = ((c0 + c1) + (c2 + c3)) * scale;
        if (r == 0) s0raw = sres; else s1raw = sres;
    }

    // softmax over 512 scores
    float m = fmaxf(s0raw, s1raw);
    #pragma unroll
    for (int off = 1; off < 64; off <<= 1) m = fmaxf(m, __shfl_xor(m, off));
    if ((tid & 63) == 0) red[tid >> 6] = m;
    __syncthreads();
    m = fmaxf(fmaxf(red[0], red[1]), fmaxf(red[2], red[3]));
    float e0 = __expf(s0raw - m), e1 = __expf(s1raw - m);
    sc[tid] = e0; sc[tid + 256] = e1;
    float lsum = e0 + e1;
    #pragma unroll
    for (int off = 1; off < 64; off <<= 1) lsum += __shfl_xor(lsum, off);
    if ((tid & 63) == 0) red[4 + (tid >> 6)] = lsum;
    __syncthreads();
    const float inv = 1.0f / ((red[4] + red[5]) + (red[6] + red[7]));

    // attn = beta @ v  (o = tid&127, each half of threads covers 256 k-rows)
    const int o  = tid & (H_ - 1);
    const int jh = tid >> 7;
    const float* vp = vb + (size_t)(b * 512 + jh * 256) * H_ + o;
    float a0=0.f,a1=0.f,a2=0.f,a3=0.f;
    for (int j = 0; j < 256; j += 4) {
        a0 += sc[jh * 256 + j + 0] * vp[(size_t)(j + 0) * H_];
        a1 += sc[jh * 256 + j + 1] * vp[(size_t)(j + 1) * H_];
        a2 += sc[jh * 256 + j + 2] * vp[(size_t)(j + 2) * H_];
        a3 += sc[jh * 256 + j + 3] * vp[(size_t)(j + 3) * H_];
    }
    pv[jh][o] = (a0 + a1) + (a2 + a3);
    __syncthreads();
    if (tid < H_) sc[tid] = (pv[0][tid] + pv[1][tid]) * inv * ww[tid];
    __syncthreads();
    if (tid == 0) {
        float rsum = 0.f;
        for (int i = 0; i < H_; ++i) rsum += sc[i];
        out[n] = rsum + bw[0];
    }
}

extern "C" void kernel_launch(void* const* d_in, const int* in_sizes, int n_in,
                              void* d_out, int out_size, void* d_ws, size_t ws_size,
                              hipStream_t stream)
{
    const float* x    = (const float*)d_in[0];
    const float* W_ih = (const float*)d_in[1];
    const float* W_hh = (const float*)d_in[2];
    const float* b_ih = (const float*)d_in[3];
    const float* b_hh = (const float*)d_in[4];
    const float* w1   = (const float*)d_in[5];
    const float* b1   = (const float*)d_in[6];
    const float* w2   = (const float*)d_in[7];
    const float* b2   = (const float*)d_in[8];
    const float* wa   = (const float*)d_in[9];
    const float* ba   = (const float*)d_in[10];
    const float* wq   = (const float*)d_in[11];
    const float* bq   = (const float*)d_in[12];
    const float* wk   = (const float*)d_in[13];
    const float* bk   = (const float*)d_in[14];
    const float* wv   = (const float*)d_in[15];
    const float* bv   = (const float*)d_in[16];
    const float* ww   = (const float*)d_in[17];
    const float* bw   = (const float*)d_in[18];

    float* ws   = (float*)d_ws;
    float* qbuf = ws;
    float* kbuf = ws + (size_t)NSEQ_ * H_;
    float* vbuf = ws + (size_t)2 * NSEQ_ * H_;

    lstm_ha_qkv<<<NSEQ_, 512, 0, stream>>>(x, W_ih, W_hh, b_ih, b_hh,
                                           w1, b1, w2, b2, wa, ba,
                                           wq, bq, wk, bk, wv, bv,
                                           qbuf, kbuf, vbuf);
    caan<<<NSEQ_, 256, 0, stream>>>(qbuf, kbuf, vbuf, ww, bw,
                                    (float*)d_out);
}

// Round 5
// 606.993 us; speedup vs baseline: 2.4797x; 2.4797x over previous
//
#include <hip/hip_runtime.h>
#include <hip/hip_bf16.h>

#define DEVI __device__ __forceinline__

constexpr int T_ = 64;   // window
constexpr int F_ = 16;   // features
constexpr int H_ = 128;  // hidden
constexpr int G_ = 512;  // 4*H gates
constexpr int NSEQ_ = 1024;  // B*M

DEVI float sigmoidf_(float x) { return 1.0f / (1.0f + __expf(-x)); }
DEVI float tanhf_(float x) {
    float a = fabsf(x);
    float e = __expf(-2.0f * a);
    float r = (1.0f - e) / (1.0f + e);
    return copysignf(r, x);
}

// One block per sequence n (0..1023), 512 threads.
// Thread tid owns gate row tid of W_hh (128 floats in VGPRs).
// __launch_bounds__(512, 2): 8 waves/block, 2 waves/EU min -> VGPR cap 256.
// Without it hipcc caps VGPR at 64 and spills whh to scratch (4.8 GB HBM
// traffic/dispatch measured in round 4).
__global__ __launch_bounds__(512, 2)
void lstm_ha_qkv(const float* __restrict__ x,
                 const float* __restrict__ W_ih, const float* __restrict__ W_hh,
                 const float* __restrict__ b_ih, const float* __restrict__ b_hh,
                 const float* __restrict__ w1, const float* __restrict__ b1,
                 const float* __restrict__ w2, const float* __restrict__ b2,
                 const float* __restrict__ wa, const float* __restrict__ ba,
                 const float* __restrict__ wq, const float* __restrict__ bq,
                 const float* __restrict__ wk, const float* __restrict__ bk,
                 const float* __restrict__ wv, const float* __restrict__ bv,
                 float* __restrict__ qout, float* __restrict__ kout,
                 float* __restrict__ vout)
{
    __shared__ alignas(16) float xs[T_ * F_];      // 4 KB
    __shared__ alignas(16) float hbuf[H_];
    __shared__ alignas(16) float cbuf[H_];
    __shared__ alignas(16) float gbuf[G_];         // 2 KB
    __shared__ alignas(16) float rep[T_][H_];      // 32 KB
    __shared__ alignas(16) float pA[4][H_], pB[4][H_], pC[4][H_];  // 6 KB
    __shared__ alignas(16) float a2s[H_];
    __shared__ alignas(16) float alphas[T_];
    __shared__ alignas(16) float srbuf[H_];
    __shared__ alignas(16) float red2[4][16][2];

    const int n   = blockIdx.x;
    const int tid = threadIdx.x;
    const int o   = tid & (H_ - 1);
    const int jc  = tid >> 7;              // 0..3 (uniform per wave)

    for (int i = tid; i < T_ * F_; i += 512) xs[i] = x[n * (T_ * F_) + i];
    if (tid < H_) { hbuf[tid] = 0.0f; cbuf[tid] = 0.0f; }

    // ---- preload weights into registers ----
    float wih[F_];
    {
        const float4* p = (const float4*)(W_ih + tid * F_);
        #pragma unroll
        for (int i = 0; i < 4; ++i) {
            float4 v4 = p[i];
            wih[4*i+0] = v4.x; wih[4*i+1] = v4.y; wih[4*i+2] = v4.z; wih[4*i+3] = v4.w;
        }
    }
    float whh[H_];
    {
        const float4* p = (const float4*)(W_hh + tid * H_);
        #pragma unroll
        for (int i = 0; i < 32; ++i) {
            float4 v4 = p[i];
            whh[4*i+0] = v4.x; whh[4*i+1] = v4.y; whh[4*i+2] = v4.z; whh[4*i+3] = v4.w;
        }
    }
    const float bias = b_ih[tid] + b_hh[tid];
    __syncthreads();

    // ---- recurrent loop ----
    #pragma unroll 1
    for (int t = 0; t < T_; ++t) {
        float a0 = bias, a1v = 0.f, a2v = 0.f, a3v = 0.f;
        {
            const float4* xp = (const float4*)(xs + t * F_);
            #pragma unroll
            for (int i = 0; i < 4; ++i) {
                float4 xv = xp[i];
                a0  += wih[4*i+0] * xv.x; a1v += wih[4*i+1] * xv.y;
                a2v += wih[4*i+2] * xv.z; a3v += wih[4*i+3] * xv.w;
            }
        }
        {
            const float4* hp = (const float4*)hbuf;
            #pragma unroll
            for (int i = 0; i < 32; ++i) {
                float4 hv = hp[i];
                a0  += whh[4*i+0] * hv.x; a1v += whh[4*i+1] * hv.y;
                a2v += whh[4*i+2] * hv.z; a3v += whh[4*i+3] * hv.w;
            }
        }
        gbuf[tid] = (a0 + a1v) + (a2v + a3v);
        __syncthreads();

        if (tid < H_) {
            float gi = sigmoidf_(gbuf[tid]);
            float gf = sigmoidf_(gbuf[H_ + tid]);
            float gg = tanhf_(gbuf[2 * H_ + tid]);
            float go = sigmoidf_(gbuf[3 * H_ + tid]);
            float c  = gf * cbuf[tid] + gi * gg;
            float h  = go * tanhf_(c);
            cbuf[tid] = c; hbuf[tid] = h; rep[t][tid] = h;
        }
        __syncthreads();
    }

    // ---- a2 = h[63] @ w2^T (+ b1 + b2 folded in) ----
    {
        float r0=0.f,r1=0.f,r2=0.f,r3=0.f;
        const float4* hq  = (const float4*)(hbuf + jc * 32);
        const float4* w2p = (const float4*)(w2 + o * H_ + jc * 32);
        #pragma unroll
        for (int i = 0; i < 8; ++i) {
            float4 hv = hq[i]; float4 wv2 = w2p[i];
            r0 += wv2.x * hv.x; r1 += wv2.y * hv.y;
            r2 += wv2.z * hv.z; r3 += wv2.w * hv.w;
        }
        pB[jc][o] = (r0 + r1) + (r2 + r3);
        __syncthreads();
        if (tid < H_)
            a2s[tid] = (pB[0][tid] + pB[1][tid]) + (pB[2][tid] + pB[3][tid])
                       + b1[tid] + b2[tid];
        __syncthreads();
    }

    // ---- alpha logits: logit[t] = sum_o wa[o]*tanh(w1[o].rep[t] + a2s[o]) ----
    // Thread (o, jc) holds the full w1 row o (whh regs dead now) and covers
    // t = jc*16 .. jc*16+15. rep[t] reads are wave-uniform -> LDS broadcast.
    {
        float w1row[H_];
        {
            const float4* p = (const float4*)(w1 + o * H_);
            #pragma unroll
            for (int i = 0; i < 32; ++i) {
                float4 v4 = p[i];
                w1row[4*i+0] = v4.x; w1row[4*i+1] = v4.y;
                w1row[4*i+2] = v4.z; w1row[4*i+3] = v4.w;
            }
        }
        const float wao = wa[o];
        const float a2o = a2s[o];
        for (int tt = 0; tt < 16; ++tt) {
            const int t = jc * 16 + tt;
            const float4* rp = (const float4*)(&rep[t][0]);
            float d0=0.f,d1=0.f,d2=0.f,d3=0.f;
            #pragma unroll
            for (int i = 0; i < 32; ++i) {
                float4 rv = rp[i];
                d0 += w1row[4*i+0] * rv.x; d1 += w1row[4*i+1] * rv.y;
                d2 += w1row[4*i+2] * rv.z; d3 += w1row[4*i+3] * rv.w;
            }
            float s = wao * tanhf_(((d0 + d1) + (d2 + d3)) + a2o);
            s += __shfl_xor(s, 1);  s += __shfl_xor(s, 2);  s += __shfl_xor(s, 4);
            s += __shfl_xor(s, 8);  s += __shfl_xor(s, 16); s += __shfl_xor(s, 32);
            if ((tid & 63) == 0) red2[jc][tt][(tid >> 6) & 1] = s;
        }
        __syncthreads();
    }

    // ---- softmax over the 64 logits (wave 0) ----
    if (tid < T_) {
        float vl = red2[tid >> 4][tid & 15][0] + red2[tid >> 4][tid & 15][1] + ba[0];
        float m = vl;
        #pragma unroll
        for (int off = 1; off < 64; off <<= 1) m = fmaxf(m, __shfl_xor(m, off));
        float e = __expf(vl - m);
        float ssum = e;
        #pragma unroll
        for (int off = 1; off < 64; off <<= 1) ssum += __shfl_xor(ssum, off);
        alphas[tid] = e / ssum;
    }
    __syncthreads();

    // ---- stock_rep = sum_t alpha[t] * rep[t] ----
    {
        float s = 0.f;
        #pragma unroll
        for (int i = 0; i < 16; ++i) {
            int t = jc * 16 + i;
            s += alphas[t] * rep[t][o];
        }
        pA[jc][o] = s;
        __syncthreads();
        if (tid < H_)
            srbuf[tid] = (pA[0][tid] + pA[1][tid]) + (pA[2][tid] + pA[3][tid]);
        __syncthreads();
    }

    // ---- q,k,v projections of stock_rep ----
    {
        float aq0=0.f,aq1=0.f, ak0=0.f,ak1=0.f, av0=0.f,av1=0.f;
        const float4* sp  = (const float4*)(srbuf + jc * 32);
        const float4* wqp = (const float4*)(wq + o * H_ + jc * 32);
        const float4* wkp = (const float4*)(wk + o * H_ + jc * 32);
        const float4* wvp = (const float4*)(wv + o * H_ + jc * 32);
        #pragma unroll
        for (int i = 0; i < 8; ++i) {
            float4 sv = sp[i];
            float4 q4 = wqp[i], k4 = wkp[i], v4 = wvp[i];
            aq0 += q4.x * sv.x + q4.z * sv.z; aq1 += q4.y * sv.y + q4.w * sv.w;
            ak0 += k4.x * sv.x + k4.z * sv.z; ak1 += k4.y * sv.y + k4.w * sv.w;
            av0 += v4.x * sv.x + v4.z * sv.z; av1 += v4.y * sv.y + v4.w * sv.w;
        }
        pA[jc][o] = aq0 + aq1; pB[jc][o] = ak0 + ak1; pC[jc][o] = av0 + av1;
        __syncthreads();
        if (tid < H_) {
            qout[n * H_ + tid] = (pA[0][tid]+pA[1][tid]) + (pA[2][tid]+pA[3][tid]) + bq[tid];
            kout[n * H_ + tid] = (pB[0][tid]+pB[1][tid]) + (pB[2][tid]+pB[3][tid]) + bk[tid];
            vout[n * H_ + tid] = (pC[0][tid]+pC[1][tid]) + (pC[2][tid]+pC[3][tid]) + bv[tid];
        }
    }
}

// Cross-asset attention: one block per (b, m) query row, 256 threads.
// Output is FLOAT32 (reference returns jnp.float32).
__global__
void caan(const float* __restrict__ qb, const float* __restrict__ kb,
          const float* __restrict__ vb, const float* __restrict__ ww,
          const float* __restrict__ bw, float* __restrict__ out)
{
    __shared__ alignas(16) float qs[H_];
    __shared__ alignas(16) float sc[512];
    __shared__ alignas(16) float red[8];
    __shared__ alignas(16) float pv[2][H_];

    const int n   = blockIdx.x;       // 0..1023
    const int b   = n >> 9;
    const int tid = threadIdx.x;

    if (tid < H_) qs[tid] = qb[n * H_ + tid];
    __syncthreads();

    const float scale = 0.08838834764831845f;  // 1/sqrt(128)
    float s0raw = 0.f, s1raw = 0.f;
    #pragma unroll
    for (int r = 0; r < 2; ++r) {
        const int j = tid + r * 256;
        const float4* kp = (const float4*)(kb + (size_t)(b * 512 + j) * H_);
        const float4* qp = (const float4*)qs;
        float c0=0.f,c1=0.f,c2=0.f,c3=0.f;
        #pragma unroll
        for (int i = 0; i < 32; ++i) {
            float4 kv = kp[i], qv = qp[i];
            c0 += kv.x * qv.x; c1 += kv.y * qv.y;
            c2 += kv.z * qv.z; c3 += kv.w * qv.w;
        }
        float sres = ((c0 + c1) + (c2 + c3)) * scale;
        if (r == 0) s0raw = sres; else s1raw = sres;
    }

    // softmax over 512 scores
    float m = fmaxf(s0raw, s1raw);
    #pragma unroll
    for (int off = 1; off < 64; off <<= 1) m = fmaxf(m, __shfl_xor(m, off));
    if ((tid & 63) == 0) red[tid >> 6] = m;
    __syncthreads();
    m = fmaxf(fmaxf(red[0], red[1]), fmaxf(red[2], red[3]));
    float e0 = __expf(s0raw - m), e1 = __expf(s1raw - m);
    sc[tid] = e0; sc[tid + 256] = e1;
    float lsum = e0 + e1;
    #pragma unroll
    for (int off = 1; off < 64; off <<= 1) lsum += __shfl_xor(lsum, off);
    if ((tid & 63) == 0) red[4 + (tid >> 6)] = lsum;
    __syncthreads();
    const float inv = 1.0f / ((red[4] + red[5]) + (red[6] + red[7]));

    // attn = beta @ v  (o = tid&127, each half of threads covers 256 k-rows)
    const int o  = tid & (H_ - 1);
    const int jh = tid >> 7;
    const float* vp = vb + (size_t)(b * 512 + jh * 256) * H_ + o;
    float a0=0.f,a1=0.f,a2=0.f,a3=0.f;
    for (int j = 0; j < 256; j += 4) {
        a0 += sc[jh * 256 + j + 0] * vp[(size_t)(j + 0) * H_];
        a1 += sc[jh * 256 + j + 1] * vp[(size_t)(j + 1) * H_];
        a2 += sc[jh * 256 + j + 2] * vp[(size_t)(j + 2) * H_];
        a3 += sc[jh * 256 + j + 3] * vp[(size_t)(j + 3) * H_];
    }
    pv[jh][o] = (a0 + a1) + (a2 + a3);
    __syncthreads();
    if (tid < H_) sc[tid] = (pv[0][tid] + pv[1][tid]) * inv * ww[tid];
    __syncthreads();
    if (tid == 0) {
        float rsum = 0.f;
        for (int i = 0; i < H_; ++i) rsum += sc[i];
        out[n] = rsum + bw[0];
    }
}

extern "C" void kernel_launch(void* const* d_in, const int* in_sizes, int n_in,
                              void* d_out, int out_size, void* d_ws, size_t ws_size,
                              hipStream_t stream)
{
    const float* x    = (const float*)d_in[0];
    const float* W_ih = (const float*)d_in[1];
    const float* W_hh = (const float*)d_in[2];
    const float* b_ih = (const float*)d_in[3];
    const float* b_hh = (const float*)d_in[4];
    const float* w1   = (const float*)d_in[5];
    const float* b1   = (const float*)d_in[6];
    const float* w2   = (const float*)d_in[7];
    const float* b2   = (const float*)d_in[8];
    const float* wa   = (const float*)d_in[9];
    const float* ba   = (const float*)d_in[10];
    const float* wq   = (const float*)d_in[11];
    const float* bq   = (const float*)d_in[12];
    const float* wk   = (const float*)d_in[13];
    const float* bk   = (const float*)d_in[14];
    const float* wv   = (const float*)d_in[15];
    const float* bv   = (const float*)d_in[16];
    const float* ww   = (const float*)d_in[17];
    const float* bw   = (const float*)d_in[18];

    float* ws   = (float*)d_ws;
    float* qbuf = ws;
    float* kbuf = ws + (size_t)NSEQ_ * H_;
    float* vbuf = ws + (size_t)2 * NSEQ_ * H_;

    lstm_ha_qkv<<<NSEQ_, 512, 0, stream>>>(x, W_ih, W_hh, b_ih, b_hh,
                                           w1, b1, w2, b2, wa, ba,
                                           wq, bq, wk, bk, wv, bv,
                                           qbuf, kbuf, vbuf);
    caan<<<NSEQ_, 256, 0, stream>>>(qbuf, kbuf, vbuf, ww, bw,
                                    (float*)d_out);
}

// Round 6
// 511.499 us; speedup vs baseline: 2.9426x; 1.1867x over previous
//
#include <hip/hip_runtime.h>
#include <hip/hip_bf16.h>

#define DEVI __device__ __forceinline__

constexpr int T_ = 64;   // window
constexpr int F_ = 16;   // features
constexpr int H_ = 128;  // hidden
constexpr int G_ = 512;  // 4*H gates
constexpr int NSEQ_ = 1024;  // B*M

DEVI float sigmoidf_(float x) { return 1.0f / (1.0f + __expf(-x)); }
DEVI float tanhf_(float x) {
    float a = fabsf(x);
    float e = __expf(-2.0f * a);
    float r = (1.0f - e) / (1.0f + e);
    return copysignf(r, x);
}

// One block per sequence n (0..1023), 1024 threads (16 waves).
// Thread (r = tid&511, hf = tid>>9) owns HALF a W_hh gate row: 64 floats in
// VGPRs. Target <=128 VGPR/thread (hard cap for 1024-thread blocks:
// 16 waves x 128 = 2048-reg file). Round-5 lesson: 128-float rows forced
// ~148 regs into AGPRs (VGPR_Count=108, occupancy 2 waves/SIMD, VALUBusy 38%)
// -- every weight use was a v_accvgpr_read.
__global__ __launch_bounds__(1024, 4)
void lstm_ha_qkv(const float* __restrict__ x,
                 const float* __restrict__ W_ih, const float* __restrict__ W_hh,
                 const float* __restrict__ b_ih, const float* __restrict__ b_hh,
                 const float* __restrict__ w1, const float* __restrict__ b1,
                 const float* __restrict__ w2, const float* __restrict__ b2,
                 const float* __restrict__ wa, const float* __restrict__ ba,
                 const float* __restrict__ wq, const float* __restrict__ bq,
                 const float* __restrict__ wk, const float* __restrict__ bk,
                 const float* __restrict__ wvm, const float* __restrict__ bv,
                 float* __restrict__ qout, float* __restrict__ kout,
                 float* __restrict__ vout)
{
    __shared__ alignas(16) float xs[T_ * F_];      // 4 KB (1024 floats)
    __shared__ alignas(16) float hbuf[H_];
    __shared__ alignas(16) float cbuf[H_];
    __shared__ alignas(16) float pG[2][G_];        // 4 KB gate partials
    __shared__ alignas(16) float rep[T_][H_];      // 32 KB
    __shared__ alignas(16) float pS[8][H_];        // 4 KB generic partials
    __shared__ alignas(16) float pB2[2][H_];       // a2 partials
    __shared__ alignas(16) float a2s[H_];
    __shared__ alignas(16) float alphas[T_];
    __shared__ alignas(16) float srbuf[H_];
    __shared__ alignas(16) float redL[T_][4];      // logit partials

    const int n   = blockIdx.x;
    const int tid = threadIdx.x;
    const int r   = tid & (G_ - 1);    // gate row 0..511
    const int hf  = tid >> 9;          // k-half 0/1 (wave-uniform)

    xs[tid] = x[n * (T_ * F_) + tid];  // T_*F_ == 1024
    if (tid < H_) { hbuf[tid] = 0.0f; cbuf[tid] = 0.0f; }

    // ---- preload weights: 64 + 8 floats per thread ----
    float wh[64];
    {
        const float4* p = (const float4*)(W_hh + r * H_ + hf * 64);
        #pragma unroll
        for (int i = 0; i < 16; ++i) {
            float4 v4 = p[i];
            wh[4*i+0] = v4.x; wh[4*i+1] = v4.y; wh[4*i+2] = v4.z; wh[4*i+3] = v4.w;
        }
    }
    float wx[8];
    {
        const float4* p = (const float4*)(W_ih + r * F_ + hf * 8);
        float4 v0 = p[0], v1 = p[1];
        wx[0]=v0.x; wx[1]=v0.y; wx[2]=v0.z; wx[3]=v0.w;
        wx[4]=v1.x; wx[5]=v1.y; wx[6]=v1.z; wx[7]=v1.w;
    }
    const float bias = (hf == 0) ? (b_ih[r] + b_hh[r]) : 0.0f;
    __syncthreads();

    // ---- recurrent loop: 64-FMA half-dot per thread per step ----
    #pragma unroll 1
    for (int t = 0; t < T_; ++t) {
        float a0 = 0.f, a1 = 0.f, a2v = 0.f, a3v = 0.f;
        {
            const float4* xp = (const float4*)(xs + t * F_ + (hf << 3));
            float4 x0 = xp[0], x1 = xp[1];
            a0  += wx[0]*x0.x; a1  += wx[1]*x0.y;
            a2v += wx[2]*x0.z; a3v += wx[3]*x0.w;
            a0  += wx[4]*x1.x; a1  += wx[5]*x1.y;
            a2v += wx[6]*x1.z; a3v += wx[7]*x1.w;
        }
        {
            const float4* hp = (const float4*)(hbuf + (hf << 6));
            #pragma unroll
            for (int i = 0; i < 16; ++i) {
                float4 hv = hp[i];
                a0  += wh[4*i+0]*hv.x; a1  += wh[4*i+1]*hv.y;
                a2v += wh[4*i+2]*hv.z; a3v += wh[4*i+3]*hv.w;
            }
        }
        pG[hf][r] = ((a0 + a1) + (a2v + a3v)) + bias;
        __syncthreads();

        if (tid < H_) {
            float gi = sigmoidf_(pG[0][tid]          + pG[1][tid]);
            float gf = sigmoidf_(pG[0][H_ + tid]     + pG[1][H_ + tid]);
            float gg = tanhf_  (pG[0][2*H_ + tid]    + pG[1][2*H_ + tid]);
            float go = sigmoidf_(pG[0][3*H_ + tid]   + pG[1][3*H_ + tid]);
            float c  = gf * cbuf[tid] + gi * gg;
            float h  = go * tanhf_(c);
            cbuf[tid] = c; hbuf[tid] = h; rep[t][tid] = h;
        }
        __syncthreads();
    }

    // ---- a2 = h[63] @ w2^T (+ b1 + b2), half-split over 256 threads ----
    if (tid < 256) {
        const int o  = tid & 127;
        const int hh = tid >> 7;
        const float4* hq  = (const float4*)(hbuf + hh * 64);
        const float4* w2p = (const float4*)(w2 + o * H_ + hh * 64);
        float r0=0.f,r1=0.f,r2=0.f,r3=0.f;
        #pragma unroll
        for (int i = 0; i < 16; ++i) {
            float4 hv = hq[i]; float4 wv2 = w2p[i];
            r0 += wv2.x*hv.x; r1 += wv2.y*hv.y; r2 += wv2.z*hv.z; r3 += wv2.w*hv.w;
        }
        pB2[hh][o] = (r0 + r1) + (r2 + r3);
    }
    __syncthreads();
    if (tid < H_)
        a2s[tid] = pB2[0][tid] + pB2[1][tid] + b1[tid] + b2[tid];
    __syncthreads();

    // ---- alpha logits: logit[t] = sum_o wa[o]*tanh(w1[o].rep[t] + a2s[o]) ----
    // hf on LANE bit 5 so the two k-halves combine via shfl_xor(32).
    // wave wv: og = wv&3 (o-group of 32), jq = wv>>2 (t-group of 16).
    {
        const int lane = tid & 63;
        const int wv_  = tid >> 6;              // 0..15
        const int hfl  = lane >> 5;             // 0/1
        const int o    = (wv_ & 3) * 32 + (lane & 31);
        const int jq   = wv_ >> 2;              // 0..3
        float w1r[64];
        {
            const float4* p = (const float4*)(w1 + o * H_ + hfl * 64);
            #pragma unroll
            for (int i = 0; i < 16; ++i) {
                float4 v4 = p[i];
                w1r[4*i+0]=v4.x; w1r[4*i+1]=v4.y; w1r[4*i+2]=v4.z; w1r[4*i+3]=v4.w;
            }
        }
        const float wao = wa[o];
        const float a2o = a2s[o];
        for (int tt = 0; tt < 16; ++tt) {
            const int t = jq * 16 + tt;
            const float4* rp = (const float4*)(&rep[t][0] + hfl * 64);
            float d0=0.f,d1=0.f,d2=0.f,d3=0.f;
            #pragma unroll
            for (int i = 0; i < 16; ++i) {
                float4 rv = rp[i];
                d0 += w1r[4*i+0]*rv.x; d1 += w1r[4*i+1]*rv.y;
                d2 += w1r[4*i+2]*rv.z; d3 += w1r[4*i+3]*rv.w;
            }
            float d = (d0 + d1) + (d2 + d3);
            d += __shfl_xor(d, 32);             // combine k-halves (full 128-dot)
            float sv = wao * tanhf_(d + a2o);   // same on lane & lane^32
            sv += __shfl_xor(sv, 1);  sv += __shfl_xor(sv, 2);
            sv += __shfl_xor(sv, 4);  sv += __shfl_xor(sv, 8);
            sv += __shfl_xor(sv, 16);           // sum 32 o's in this half-wave
            if (lane == 0) redL[t][wv_ & 3] = sv;
        }
    }
    __syncthreads();

    // ---- softmax over the 64 logits (wave 0) ----
    if (tid < T_) {
        float vl = (redL[tid][0] + redL[tid][1]) + (redL[tid][2] + redL[tid][3])
                   + ba[0];
        float m = vl;
        #pragma unroll
        for (int off = 1; off < 64; off <<= 1) m = fmaxf(m, __shfl_xor(m, off));
        float e = __expf(vl - m);
        float ssum = e;
        #pragma unroll
        for (int off = 1; off < 64; off <<= 1) ssum += __shfl_xor(ssum, off);
        alphas[tid] = e / ssum;
    }
    __syncthreads();

    // ---- stock_rep = sum_t alpha[t] * rep[t] ----
    {
        const int o = tid & 127;
        const int s = tid >> 7;        // 0..7, 8 t's each
        float acc = 0.f;
        #pragma unroll
        for (int i = 0; i < 8; ++i) {
            int t = s * 8 + i;
            acc += alphas[t] * rep[t][o];
        }
        pS[s][o] = acc;
        __syncthreads();
        if (tid < H_)
            srbuf[tid] = ((pS[0][tid]+pS[1][tid]) + (pS[2][tid]+pS[3][tid]))
                       + ((pS[4][tid]+pS[5][tid]) + (pS[6][tid]+pS[7][tid]));
        __syncthreads();
    }

    // ---- q,k,v projections (6 of 8 thread-groups: mat x k-half) ----
    {
        const int o   = tid & 127;
        const int grp = tid >> 7;      // 0..7
        if (grp < 6) {
            const int mat = grp >> 1;  // 0=q 1=k 2=v
            const int hh  = grp & 1;
            const float* wm = (mat == 0) ? wq : (mat == 1) ? wk : wvm;
            const float4* sp = (const float4*)(srbuf + hh * 64);
            const float4* wp = (const float4*)(wm + o * H_ + hh * 64);
            float r0=0.f,r1=0.f,r2=0.f,r3=0.f;
            #pragma unroll
            for (int i = 0; i < 16; ++i) {
                float4 sv = sp[i]; float4 wv4 = wp[i];
                r0 += wv4.x*sv.x; r1 += wv4.y*sv.y; r2 += wv4.z*sv.z; r3 += wv4.w*sv.w;
            }
            pS[grp][o] = (r0 + r1) + (r2 + r3);
        }
        __syncthreads();
        if (tid < H_)
            qout[n * H_ + tid] = pS[0][tid] + pS[1][tid] + bq[tid];
        else if (tid < 2 * H_)
            kout[n * H_ + (tid - H_)]   = pS[2][tid - H_] + pS[3][tid - H_] + bk[tid - H_];
        else if (tid < 3 * H_)
            vout[n * H_ + (tid - 2*H_)] = pS[4][tid - 2*H_] + pS[5][tid - 2*H_] + bv[tid - 2*H_];
    }
}

// Cross-asset attention: one block per (b, m) query row, 256 threads.
// Output is FLOAT32 (reference returns jnp.float32).
__global__ __launch_bounds__(256, 4)
void caan(const float* __restrict__ qb, const float* __restrict__ kb,
          const float* __restrict__ vb, const float* __restrict__ ww,
          const float* __restrict__ bw, float* __restrict__ out)
{
    __shared__ alignas(16) float qs[H_];
    __shared__ alignas(16) float sc[512];
    __shared__ alignas(16) float red[8];
    __shared__ alignas(16) float pv[2][H_];

    const int n   = blockIdx.x;       // 0..1023
    const int b   = n >> 9;
    const int tid = threadIdx.x;

    if (tid < H_) qs[tid] = qb[n * H_ + tid];
    __syncthreads();

    const float scale = 0.08838834764831845f;  // 1/sqrt(128)
    float s0raw = 0.f, s1raw = 0.f;
    #pragma unroll
    for (int r = 0; r < 2; ++r) {
        const int j = tid + r * 256;
        const float4* kp = (const float4*)(kb + (size_t)(b * 512 + j) * H_);
        const float4* qp = (const float4*)qs;
        float c0=0.f,c1=0.f,c2=0.f,c3=0.f;
        #pragma unroll
        for (int i = 0; i < 32; ++i) {
            float4 kv = kp[i], qv = qp[i];
            c0 += kv.x * qv.x; c1 += kv.y * qv.y;
            c2 += kv.z * qv.z; c3 += kv.w * qv.w;
        }
        float sres = ((c0 + c1) + (c2 + c3)) * scale;
        if (r == 0) s0raw = sres; else s1raw = sres;
    }

    // softmax over 512 scores
    float m = fmaxf(s0raw, s1raw);
    #pragma unroll
    for (int off = 1; off < 64; off <<= 1) m = fmaxf(m, __shfl_xor(m, off));
    if ((tid & 63) == 0) red[tid >> 6] = m;
    __syncthreads();
    m = fmaxf(fmaxf(red[0], red[1]), fmaxf(red[2], red[3]));
    float e0 = __expf(s0raw - m), e1 = __expf(s1raw - m);
    sc[tid] = e0; sc[tid + 256] = e1;
    float lsum = e0 + e1;
    #pragma unroll
    for (int off = 1; off < 64; off <<= 1) lsum += __shfl_xor(lsum, off);
    if ((tid & 63) == 0) red[4 + (tid >> 6)] = lsum;
    __syncthreads();
    const float inv = 1.0f / ((red[4] + red[5]) + (red[6] + red[7]));

    // attn = beta @ v  (o = tid&127, each half of threads covers 256 k-rows)
    const int o  = tid & (H_ - 1);
    const int jh = tid >> 7;
    const float* vp = vb + (size_t)(b * 512 + jh * 256) * H_ + o;
    float a0=0.f,a1=0.f,a2=0.f,a3=0.f;
    for (int j = 0; j < 256; j += 4) {
        a0 += sc[jh * 256 + j + 0] * vp[(size_t)(j + 0) * H_];
        a1 += sc[jh * 256 + j + 1] * vp[(size_t)(j + 1) * H_];
        a2 += sc[jh * 256 + j + 2] * vp[(size_t)(j + 2) * H_];
        a3 += sc[jh * 256 + j + 3] * vp[(size_t)(j + 3) * H_];
    }
    pv[jh][o] = (a0 + a1) + (a2 + a3);
    __syncthreads();
    if (tid < H_) {
        float s = (pv[0][tid] + pv[1][tid]) * inv * ww[tid];
        s += __shfl_xor(s, 1);  s += __shfl_xor(s, 2);  s += __shfl_xor(s, 4);
        s += __shfl_xor(s, 8);  s += __shfl_xor(s, 16); s += __shfl_xor(s, 32);
        if ((tid & 63) == 0) red[tid >> 6] = s;
    }
    __syncthreads();
    if (tid == 0) out[n] = red[0] + red[1] + bw[0];
}

extern "C" void kernel_launch(void* const* d_in, const int* in_sizes, int n_in,
                              void* d_out, int out_size, void* d_ws, size_t ws_size,
                              hipStream_t stream)
{
    const float* x    = (const float*)d_in[0];
    const float* W_ih = (const float*)d_in[1];
    const float* W_hh = (const float*)d_in[2];
    const float* b_ih = (const float*)d_in[3];
    const float* b_hh = (const float*)d_in[4];
    const float* w1   = (const float*)d_in[5];
    const float* b1   = (const float*)d_in[6];
    const float* w2   = (const float*)d_in[7];
    const float* b2   = (const float*)d_in[8];
    const float* wa   = (const float*)d_in[9];
    const float* ba   = (const float*)d_in[10];
    const float* wq   = (const float*)d_in[11];
    const float* bq   = (const float*)d_in[12];
    const float* wk   = (const float*)d_in[13];
    const float* bk   = (const float*)d_in[14];
    const float* wv   = (const float*)d_in[15];
    const float* bv   = (const float*)d_in[16];
    const float* ww   = (const float*)d_in[17];
    const float* bw   = (const float*)d_in[18];

    float* ws   = (float*)d_ws;
    float* qbuf = ws;
    float* kbuf = ws + (size_t)NSEQ_ * H_;
    float* vbuf = ws + (size_t)2 * NSEQ_ * H_;

    lstm_ha_qkv<<<NSEQ_, 1024, 0, stream>>>(x, W_ih, W_hh, b_ih, b_hh,
                                            w1, b1, w2, b2, wa, ba,
                                            wq, bq, wk, bk, wv, bv,
                                            qbuf, kbuf, vbuf);
    caan<<<NSEQ_, 256, 0, stream>>>(qbuf, kbuf, vbuf, ww, bw,
                                    (float*)d_out);
}

// Round 7
// 312.877 us; speedup vs baseline: 4.8106x; 1.6348x over previous
//
#include <hip/hip_runtime.h>
#include <hip/hip_bf16.h>

#define DEVI __device__ __forceinline__

typedef float f32x4 __attribute__((ext_vector_type(4)));
typedef short s16x8 __attribute__((ext_vector_type(8)));

constexpr int T_ = 64;    // window
constexpr int F_ = 16;    // features
constexpr int H_ = 128;   // hidden
constexpr int NSEQ_ = 1024;
constexpr int NB_ = 16;   // sequences per block
constexpr int NBLK_ = NSEQ_ / NB_;  // 64 blocks

DEVI float sigmoidf_(float x) { return 1.0f / (1.0f + __expf(-x)); }
DEVI float tanhf_(float x) {
    float a = fabsf(x);
    float e = __expf(-2.0f * a);
    return copysignf((1.0f - e) / (1.0f + e), x);
}
DEVI ushort f2bf(float f) {             // fp32 -> bf16 bits, RNE
    unsigned u = __float_as_uint(f);
    return (ushort)((u + 0x7fffu + ((u >> 16) & 1u)) >> 16);
}
DEVI float bf2f(ushort b) { return __uint_as_float(((unsigned)b) << 16); }

#define MFMA16(A,B,C) __builtin_amdgcn_mfma_f32_16x16x32_bf16((A),(B),(C),0,0,0)

// LDS pool (single static buffer, phase-aliased; 51728 B < 64 KB):
//  recurrence: hhi ushort[16][168] @0 (5376B), hlo @5376 (5376B)
//  epilogue:   w1bf ushort[128][136] @0 (34816B)  [hh dead]
//              a2s  float[16][128]  @34816 (8192B)  [aliased by srbuf in E4+]
//              logitb float[16][64] @43008 (4096B)
//              alph   float[16][64] @47104 (4096B)
//              wab    float[132]    @51200 (528B)
constexpr int POOL_BYTES = 51728;

// Fused kernel: LSTM recurrence (MFMA, bf16 hi/lo split) + temporal attention
// + q/k/v projections for NB_=16 sequences per block. 512 threads, 8 waves.
// Wave w owns gate rows {16w+128g : g=0..3}: the four gates of hidden block
// j in [16w,16w+16) land in the SAME lane of the C-fragment -> in-register
// cell update, c-state in VGPRs.
__global__ __launch_bounds__(512, 2)
void alphastock_main(const float* __restrict__ x,
                     const float* __restrict__ W_ih, const float* __restrict__ W_hh,
                     const float* __restrict__ b_ih, const float* __restrict__ b_hh,
                     const float* __restrict__ w1, const float* __restrict__ b1,
                     const float* __restrict__ w2, const float* __restrict__ b2,
                     const float* __restrict__ wa, const float* __restrict__ ba,
                     const float* __restrict__ wq, const float* __restrict__ bq,
                     const float* __restrict__ wk, const float* __restrict__ bk,
                     const float* __restrict__ wvm, const float* __restrict__ bv,
                     ushort* __restrict__ rep,   // [1024][64][128] bf16 ws
                     ushort* __restrict__ xgw,   // [1024][64][32] bf16 ws (x hi|lo)
                     float* __restrict__ qout, float* __restrict__ kout,
                     float* __restrict__ vout)
{
    __shared__ alignas(16) char pool_[POOL_BYTES];
    ushort* hhi   = (ushort*)pool_;                    // [16][168]
    ushort* hlo   = hhi + 16 * 168;
    ushort* w1bf  = (ushort*)pool_;                    // [128][136] (epilogue)
    float*  a2s   = (float*)(pool_ + 34816);           // [16][128]; srbuf alias
    float*  logitb= (float*)(pool_ + 43008);           // [16][64]
    float*  alph  = (float*)(pool_ + 47104);           // [16][64]
    float*  wab   = (float*)(pool_ + 51200);           // [0..127]=wa, [128]=ba

    const int tid  = threadIdx.x;
    const int wv   = tid >> 6;        // wave 0..7
    const int lane = tid & 63;
    const int lN   = lane & 15;       // frag col (seq) / A-row
    const int lK   = lane >> 4;       // k-group 0..3
    const int nb   = blockIdx.x * NB_;

    // ---- prologue: zero h buffers; build x hi/lo bf16 in ws ----
    for (int i = tid; i < 2 * 16 * 168; i += 512) ((ushort*)pool_)[i] = 0;
    for (int idx = tid; idx < NB_ * T_ * F_; idx += 512) {   // 16384
        int s = idx >> 10, rem = idx & 1023;                 // rem = t*16+f
        int t = rem >> 4, f = rem & 15;
        float v = x[(size_t)(nb + s) * 1024 + rem];
        ushort hb = f2bf(v);
        ushort lb = f2bf(v - bf2f(hb));
        size_t base = ((size_t)(nb + s) * T_ + t) * 32;
        xgw[base + f] = hb; xgw[base + 16 + f] = lb;
    }

    // ---- A-fragments: Whh (k 0..127) | Wih vs x_hi (128..143) | Wih vs x_lo
    // (144..159). Row ra = 128g + 16wv + lN; k = ks*32 + lK*8 + i.
    s16x8 ahi[4][5], alo[4][5];
    #pragma unroll
    for (int g = 0; g < 4; ++g) {
        const int ra = 128 * g + 16 * wv + lN;
        #pragma unroll
        for (int ks = 0; ks < 5; ++ks) {
            float w[8];
            if (ks < 4) {
                const float4* p = (const float4*)(W_hh + (size_t)ra * 128 + ks * 32 + lK * 8);
                float4 v0 = p[0], v1 = p[1];
                w[0]=v0.x; w[1]=v0.y; w[2]=v0.z; w[3]=v0.w;
                w[4]=v1.x; w[5]=v1.y; w[6]=v1.z; w[7]=v1.w;
            } else {
                const int kk = (lK & 1) * 8;   // lK 0,1 -> x_hi cols; 2,3 -> x_lo cols (same W_ih)
                const float4* p = (const float4*)(W_ih + (size_t)ra * 16 + kk);
                float4 v0 = p[0], v1 = p[1];
                w[0]=v0.x; w[1]=v0.y; w[2]=v0.z; w[3]=v0.w;
                w[4]=v1.x; w[5]=v1.y; w[6]=v1.z; w[7]=v1.w;
            }
            #pragma unroll
            for (int i = 0; i < 8; ++i) {
                ushort hb = f2bf(w[i]);
                ahi[g][ks][i] = (short)hb;
                alo[g][ks][i] = (short)f2bf(w[i] - bf2f(hb));
            }
        }
    }
    // biases for this lane's C rows: row = 128g + 16wv + 4lK + r
    float bias[4][4];
    #pragma unroll
    for (int g = 0; g < 4; ++g)
        #pragma unroll
        for (int r = 0; r < 4; ++r) {
            int rr = 128 * g + 16 * wv + 4 * lK + r;
            bias[g][r] = b_ih[rr] + b_hh[rr];
        }
    float cst[4] = {0.f, 0.f, 0.f, 0.f};
    __syncthreads();

    // ---- recurrent loop ----
    const int hoff = lN * 168;
    const int jo   = 16 * wv + 4 * lK;
    #pragma unroll 1
    for (int t = 0; t < T_; ++t) {
        f32x4 acc0 = {0.f,0.f,0.f,0.f}, acc1 = {0.f,0.f,0.f,0.f};
        f32x4 acc2 = {0.f,0.f,0.f,0.f}, acc3 = {0.f,0.f,0.f,0.f};
        #pragma unroll
        for (int ks = 0; ks < 4; ++ks) {
            s16x8 bh = *(const s16x8*)(hhi + hoff + ks * 32 + lK * 8);
            s16x8 bl = *(const s16x8*)(hlo + hoff + ks * 32 + lK * 8);
            acc0 = MFMA16(ahi[0][ks], bh, acc0); acc0 = MFMA16(ahi[0][ks], bl, acc0); acc0 = MFMA16(alo[0][ks], bh, acc0);
            acc1 = MFMA16(ahi[1][ks], bh, acc1); acc1 = MFMA16(ahi[1][ks], bl, acc1); acc1 = MFMA16(alo[1][ks], bh, acc1);
            acc2 = MFMA16(ahi[2][ks], bh, acc2); acc2 = MFMA16(ahi[2][ks], bl, acc2); acc2 = MFMA16(alo[2][ks], bh, acc2);
            acc3 = MFMA16(ahi[3][ks], bh, acc3); acc3 = MFMA16(ahi[3][ks], bl, acc3); acc3 = MFMA16(alo[3][ks], bh, acc3);
        }
        {   // x-part: B holds [x_hi(16); x_lo(16)]; (Whi+Wlo)@(xhi+xlo) exact-ish
            s16x8 bx = *(const s16x8*)(xgw + ((size_t)(nb + lN) * T_ + t) * 32 + lK * 8);
            acc0 = MFMA16(ahi[0][4], bx, acc0); acc0 = MFMA16(alo[0][4], bx, acc0);
            acc1 = MFMA16(ahi[1][4], bx, acc1); acc1 = MFMA16(alo[1][4], bx, acc1);
            acc2 = MFMA16(ahi[2][4], bx, acc2); acc2 = MFMA16(alo[2][4], bx, acc2);
            acc3 = MFMA16(ahi[3][4], bx, acc3); acc3 = MFMA16(alo[3][4], bx, acc3);
        }
        __syncthreads();   // all B-frag reads done -> safe to overwrite h

        unsigned phx = 0, phy = 0, plx = 0, ply = 0;
        #pragma unroll
        for (int r = 0; r < 4; ++r) {
            float ii = sigmoidf_(acc0[r] + bias[0][r]);
            float ff = sigmoidf_(acc1[r] + bias[1][r]);
            float gg = tanhf_  (acc2[r] + bias[2][r]);
            float oo = sigmoidf_(acc3[r] + bias[3][r]);
            float c  = ff * cst[r] + ii * gg;
            cst[r] = c;
            float h  = oo * tanhf_(c);
            ushort hb = f2bf(h);
            ushort lb = f2bf(h - bf2f(hb));
            if      (r == 0) { phx = hb;                plx = lb; }
            else if (r == 1) { phx |= (unsigned)hb<<16; plx |= (unsigned)lb<<16; }
            else if (r == 2) { phy = hb;                ply = lb; }
            else             { phy |= (unsigned)hb<<16; ply |= (unsigned)lb<<16; }
        }
        uint2 uh; uh.x = phx; uh.y = phy;
        uint2 ul; ul.x = plx; ul.y = ply;
        *(uint2*)(hhi + hoff + jo) = uh;                                   // next-step B
        *(uint2*)(hlo + hoff + jo) = ul;
        *(uint2*)(rep + ((size_t)(nb + lN) * T_ + t) * H_ + jo) = uh;      // bf16 rep
        __syncthreads();
    }

    // ================= epilogue (16 seqs in this block) =================
    // E0: stage w1 (bf16) + wa/ba into LDS (hh region dead -> alias)
    for (int idx = tid; idx < 128 * 128; idx += 512) {
        int o = idx >> 7, k = idx & 127;
        w1bf[o * 136 + k] = f2bf(w1[idx]);
    }
    if (tid < 128) wab[tid] = wa[tid];
    if (tid == 128) wab[128] = ba[0];
    __syncthreads();

    // E1: a2[s][o] = h63 @ w2^T + b1 + b2   (wave 0 only; 32 MFMA)
    if (wv == 0) {
        s16x8 ar[4];
        #pragma unroll
        for (int ks = 0; ks < 4; ++ks)
            ar[ks] = *(const s16x8*)(rep + ((size_t)(nb + lN) * T_ + 63) * H_ + ks * 32 + lK * 8);
        #pragma unroll
        for (int nt = 0; nt < 8; ++nt) {
            f32x4 acc = {0.f,0.f,0.f,0.f};
            const int o = 16 * nt + lN;
            #pragma unroll
            for (int ks = 0; ks < 4; ++ks) {
                const float4* p = (const float4*)(w2 + (size_t)o * 128 + ks * 32 + lK * 8);
                float4 v0 = p[0], v1 = p[1];
                s16x8 bb;
                bb[0]=(short)f2bf(v0.x); bb[1]=(short)f2bf(v0.y); bb[2]=(short)f2bf(v0.z); bb[3]=(short)f2bf(v0.w);
                bb[4]=(short)f2bf(v1.x); bb[5]=(short)f2bf(v1.y); bb[6]=(short)f2bf(v1.z); bb[7]=(short)f2bf(v1.w);
                acc = MFMA16(ar[ks], bb, acc);
            }
            float bb12 = b1[o] + b2[o];
            #pragma unroll
            for (int r = 0; r < 4; ++r)
                a2s[(4 * lK + r) * 128 + o] = acc[r] + bb12;
        }
    }
    __syncthreads();

    // E2: logits[t] = sum_o wa[o] * tanh(A1[t][o] + a2[o]);  A1 = rep @ w1^T
    #pragma unroll 1
    for (int sq = 0; sq < 2; ++sq) {
        const int seq = 2 * wv + sq;
        #pragma unroll 1
        for (int mt = 0; mt < 4; ++mt) {
            s16x8 ar[4];
            #pragma unroll
            for (int ks = 0; ks < 4; ++ks)
                ar[ks] = *(const s16x8*)(rep + ((size_t)(nb + seq) * T_ + 16 * mt + lN) * H_ + ks * 32 + lK * 8);
            float part[4] = {0.f,0.f,0.f,0.f};
            #pragma unroll
            for (int nt = 0; nt < 8; ++nt) {
                f32x4 acc = {0.f,0.f,0.f,0.f};
                #pragma unroll
                for (int ks = 0; ks < 4; ++ks)
                    acc = MFMA16(ar[ks],
                                 *(const s16x8*)(w1bf + (lN + 16 * nt) * 136 + ks * 32 + lK * 8),
                                 acc);
                const int o = lN + 16 * nt;
                const float wao = wab[o];
                const float a2o = a2s[seq * 128 + o];
                #pragma unroll
                for (int r = 0; r < 4; ++r)
                    part[r] += wao * tanhf_(acc[r] + a2o);
            }
            #pragma unroll
            for (int r = 0; r < 4; ++r) {
                part[r] += __shfl_xor(part[r], 1);
                part[r] += __shfl_xor(part[r], 2);
                part[r] += __shfl_xor(part[r], 4);
                part[r] += __shfl_xor(part[r], 8);
            }
            if (lN == 0) {
                float4 st; st.x = part[0]; st.y = part[1]; st.z = part[2]; st.w = part[3];
                *(float4*)(logitb + seq * 64 + 16 * mt + 4 * lK) = st;  // t = 16mt+4lK+r
            }
        }
    }
    __syncthreads();

    // E3: softmax over 64 logits, 2 seqs per wave
    #pragma unroll 1
    for (int sq = 0; sq < 2; ++sq) {
        const int seq = 2 * wv + sq;
        float vl = logitb[seq * 64 + lane] + wab[128];
        float m = vl;
        #pragma unroll
        for (int off = 1; off < 64; off <<= 1) m = fmaxf(m, __shfl_xor(m, off));
        float e = __expf(vl - m);
        float ss = e;
        #pragma unroll
        for (int off = 1; off < 64; off <<= 1) ss += __shfl_xor(ss, off);
        alph[seq * 64 + lane] = e / ss;
    }
    __syncthreads();

    // E4: stock_rep[s][h] = sum_t alpha * rep   (fp32, into a2s alias)
    {
        const int s = tid >> 5, hq = tid & 31;  // 4 h per thread
        float a0 = 0.f, a1 = 0.f, a2v = 0.f, a3 = 0.f;
        const ushort* rp = rep + (size_t)(nb + s) * T_ * H_ + hq * 4;
        for (int t = 0; t < T_; ++t) {
            float al = alph[s * 64 + t];
            uint2 rv = *(const uint2*)(rp + (size_t)t * H_);
            a0  += al * bf2f((ushort)(rv.x & 0xffff));
            a1  += al * bf2f((ushort)(rv.x >> 16));
            a2v += al * bf2f((ushort)(rv.y & 0xffff));
            a3  += al * bf2f((ushort)(rv.y >> 16));
        }
        float4 st; st.x = a0; st.y = a1; st.z = a2v; st.w = a3;
        *(float4*)(a2s + s * 128 + hq * 4) = st;   // srbuf alias (a2s dead)
    }
    __syncthreads();

    // E5: q,k,v = sr @ W^T + b   (fp32 VALU: bf16 q/k would poison the
    // 512-wide attention softmax). Thread: o = tid&127, 4 seqs each.
    {
        const float* sr = a2s;
        const int o = tid & 127, sg = tid >> 7;
        float aq[4] = {0,0,0,0}, ak[4] = {0,0,0,0}, av[4] = {0,0,0,0};
        for (int k = 0; k < 128; k += 4) {
            float4 q4 = *(const float4*)(wq  + (size_t)o * 128 + k);
            float4 k4 = *(const float4*)(wk  + (size_t)o * 128 + k);
            float4 v4 = *(const float4*)(wvm + (size_t)o * 128 + k);
            #pragma unroll
            for (int j = 0; j < 4; ++j) {
                float4 s4 = *(const float4*)(sr + (4 * sg + j) * 128 + k);
                aq[j] += q4.x*s4.x + q4.y*s4.y + q4.z*s4.z + q4.w*s4.w;
                ak[j] += k4.x*s4.x + k4.y*s4.y + k4.z*s4.z + k4.w*s4.w;
                av[j] += v4.x*s4.x + v4.y*s4.y + v4.z*s4.z + v4.w*s4.w;
            }
        }
        #pragma unroll
        for (int j = 0; j < 4; ++j) {
            const int s = 4 * sg + j;
            qout[(size_t)(nb + s) * H_ + o] = aq[j] + bq[o];
            kout[(size_t)(nb + s) * H_ + o] = ak[j] + bk[o];
            vout[(size_t)(nb + s) * H_ + o] = av[j] + bv[o];
        }
    }
}

// Cross-asset attention: one block per (b, m) query row, 256 threads. fp32 out.
__global__ __launch_bounds__(256, 4)
void caan(const float* __restrict__ qb, const float* __restrict__ kb,
          const float* __restrict__ vb, const float* __restrict__ ww,
          const float* __restrict__ bw, float* __restrict__ out)
{
    __shared__ alignas(16) float qs[H_];
    __shared__ alignas(16) float sc[512];
    __shared__ alignas(16) float red[8];
    __shared__ alignas(16) float pv[2][H_];

    const int n   = blockIdx.x;
    const int b   = n >> 9;
    const int tid = threadIdx.x;

    if (tid < H_) qs[tid] = qb[n * H_ + tid];
    __syncthreads();

    const float scale = 0.08838834764831845f;  // 1/sqrt(128)
    float s0raw = 0.f, s1raw = 0.f;
    #pragma unroll
    for (int r = 0; r < 2; ++r) {
        const int j = tid + r * 256;
        const float4* kp = (const float4*)(kb + (size_t)(b * 512 + j) * H_);
        const float4* qp = (const float4*)qs;
        float c0=0.f,c1=0.f,c2=0.f,c3=0.f;
        #pragma unroll
        for (int i = 0; i < 32; ++i) {
            float4 kv = kp[i], qv = qp[i];
            c0 += kv.x*qv.x; c1 += kv.y*qv.y; c2 += kv.z*qv.z; c3 += kv.w*qv.w;
        }
        float sres = ((c0 + c1) + (c2 + c3)) * scale;
        if (r == 0) s0raw = sres; else s1raw = sres;
    }

    float m = fmaxf(s0raw, s1raw);
    #pragma unroll
    for (int off = 1; off < 64; off <<= 1) m = fmaxf(m, __shfl_xor(m, off));
    if ((tid & 63) == 0) red[tid >> 6] = m;
    __syncthreads();
    m = fmaxf(fmaxf(red[0], red[1]), fmaxf(red[2], red[3]));
    float e0 = __expf(s0raw - m), e1 = __expf(s1raw - m);
    sc[tid] = e0; sc[tid + 256] = e1;
    float lsum = e0 + e1;
    #pragma unroll
    for (int off = 1; off < 64; off <<= 1) lsum += __shfl_xor(lsum, off);
    if ((tid & 63) == 0) red[4 + (tid >> 6)] = lsum;
    __syncthreads();
    const float inv = 1.0f / ((red[4] + red[5]) + (red[6] + red[7]));

    const int o  = tid & (H_ - 1);
    const int jh = tid >> 7;
    const float* vp = vb + (size_t)(b * 512 + jh * 256) * H_ + o;
    float a0=0.f,a1=0.f,a2=0.f,a3=0.f;
    for (int j = 0; j < 256; j += 4) {
        a0 += sc[jh*256 + j + 0] * vp[(size_t)(j + 0) * H_];
        a1 += sc[jh*256 + j + 1] * vp[(size_t)(j + 1) * H_];
        a2 += sc[jh*256 + j + 2] * vp[(size_t)(j + 2) * H_];
        a3 += sc[jh*256 + j + 3] * vp[(size_t)(j + 3) * H_];
    }
    pv[jh][o] = (a0 + a1) + (a2 + a3);
    __syncthreads();
    if (tid < H_) {
        float s = (pv[0][tid] + pv[1][tid]) * inv * ww[tid];
        s += __shfl_xor(s, 1);  s += __shfl_xor(s, 2);  s += __shfl_xor(s, 4);
        s += __shfl_xor(s, 8);  s += __shfl_xor(s, 16); s += __shfl_xor(s, 32);
        if ((tid & 63) == 0) red[tid >> 6] = s;
    }
    __syncthreads();
    if (tid == 0) out[n] = red[0] + red[1] + bw[0];
}

extern "C" void kernel_launch(void* const* d_in, const int* in_sizes, int n_in,
                              void* d_out, int out_size, void* d_ws, size_t ws_size,
                              hipStream_t stream)
{
    const float* x    = (const float*)d_in[0];
    const float* W_ih = (const float*)d_in[1];
    const float* W_hh = (const float*)d_in[2];
    const float* b_ih = (const float*)d_in[3];
    const float* b_hh = (const float*)d_in[4];
    const float* w1   = (const float*)d_in[5];
    const float* b1   = (const float*)d_in[6];
    const float* w2   = (const float*)d_in[7];
    const float* b2   = (const float*)d_in[8];
    const float* wa   = (const float*)d_in[9];
    const float* ba   = (const float*)d_in[10];
    const float* wq   = (const float*)d_in[11];
    const float* bq   = (const float*)d_in[12];
    const float* wk   = (const float*)d_in[13];
    const float* bk   = (const float*)d_in[14];
    const float* wv   = (const float*)d_in[15];
    const float* bv   = (const float*)d_in[16];
    const float* ww   = (const float*)d_in[17];
    const float* bw   = (const float*)d_in[18];

    float* ws   = (float*)d_ws;
    float* qbuf = ws;                              // 1024*128 f32
    float* kbuf = ws + (size_t)NSEQ_ * H_;
    float* vbuf = ws + (size_t)2 * NSEQ_ * H_;
    ushort* rep = (ushort*)(ws + (size_t)3 * NSEQ_ * H_);        // 16 MB bf16
    ushort* xgw = rep + (size_t)NSEQ_ * T_ * H_;                 // 4 MB bf16

    alphastock_main<<<NBLK_, 512, 0, stream>>>(x, W_ih, W_hh, b_ih, b_hh,
                                               w1, b1, w2, b2, wa, ba,
                                               wq, bq, wk, bk, wv, bv,
                                               rep, xgw, qbuf, kbuf, vbuf);
    caan<<<NSEQ_, 256, 0, stream>>>(qbuf, kbuf, vbuf, ww, bw, (float*)d_out);
}